// Round 4
// baseline (33.106 us; speedup 1.0000x reference)
//
#include <hip/hip_runtime.h>

#define IMH 384
#define IMW 384
#define OH 378
#define OW 378
#define NB 64
#define SROWS 9
#define INROWS 15          // SROWS + 6
#define NSTRIP 42          // 42*9 = 378 exactly
#define NSEG 15            // ceil(378/26) column segments per strip
#define BLOCK 256          // 4 waves = 16 DPP groups of 16 lanes
#define GSTRIDE 26         // output cols per group (13 lanes x 2 cols)
#define TPB (NSTRIP * NSEG)          // 630 tasks per batch
#define NTASK (NB * TPB)             // 40320 group-tasks
#define NBLOCKS (NTASK / 16)         // 2520 blocks, no dead groups
#define ACCSTRIDE 32                 // one 128B line per batch slot

// Round 13: R12 (2x waves) was FLAT vs R10 -> concurrency is not the
// limiter; exposed HBM latency is. The manual depth-2 px/py ring issues
// each load only ~2 rows (~240 cy) before its use, vs ~900 cy HBM miss
// (poison fills flush L3 every iter). R11's capture showed VGPR=40 at an
// 85-reg budget: the allocator has ~45 idle regs that the ring's
// slot-recycling structurally prevents it from using for deeper prefetch.
// Fix: DELETE the ring. Direct per-row loads in the fully-unrolled body;
// all 15 row-load pairs are independent w/ static offsets -> scheduler
// may hoist loads 4-6 rows deep under the (6,8) budget. Also drops the
// per-row min() row clamp (y0+r <= 383 exactly in range).
// Diagnostic: VGPR should RISE to ~65-85. If it stays ~40, the compiler
// refused -> next round = wave-private LDS ring via global_load_lds.

template <int CTRL>
__device__ __forceinline__ float dpp_sh(float v) {
    return __int_as_float(__builtin_amdgcn_update_dpp(
        0, __float_as_int(v), CTRL, 0xf, 0xf, true));
}

__device__ __forceinline__ float2 f2add(float2 a, float2 b) { return make_float2(a.x + b.x, a.y + b.y); }
__device__ __forceinline__ float2 f2sub(float2 a, float2 b) { return make_float2(a.x - b.x, a.y - b.y); }
__device__ __forceinline__ float2 f2mul(float2 a, float2 b) { return make_float2(a.x * b.x, a.y * b.y); }
__device__ __forceinline__ float2 f2fma(float2 a, float2 b, float2 c) {
    return make_float2(fmaf(a.x, b.x, c.x), fmaf(a.y, b.y, c.y));
}
__device__ __forceinline__ float2 f2fnma(float2 a, float2 b, float2 c) {  // c - a*b
    return make_float2(fmaf(-a.x, b.x, c.x), fmaf(-a.y, b.y, c.y));
}
__device__ __forceinline__ float2 f2fms(float2 a, float s, float2 c) {    // a*s - c
    return make_float2(fmaf(a.x, s, -c.x), fmaf(a.y, s, -c.y));
}
__device__ __forceinline__ float2 f2s(float s) { return make_float2(s, s); }

__global__ __launch_bounds__(BLOCK)
__attribute__((amdgpu_waves_per_eu(6, 8)))
void ssim_kernel(
    const float* __restrict__ X, const float* __restrict__ Y,
    const float* __restrict__ data_range, float* __restrict__ acc)
{
    const int tid = threadIdx.x;
    const int g   = tid >> 4;                 // DPP group 0..15
    const int j   = tid & 15;                 // lane within group

    // ---- linearized task decode: t -> (b, strip, seg) ----
    const int t     = blockIdx.x * (BLOCK / 16) + g;
    const int b     = t / TPB;                      // /630 (magic mul)
    const int r2    = t - b * TPB;
    const int strip = r2 / NSEG;                    // /15
    const int seg   = r2 - strip * NSEG;
    const int y0    = strip * SROWS;

    const int ce  = seg * GSTRIDE + 2 * j;    // lane's even column (global)
    const int cin = min(ce, IMW - 2);         // clamped, even -> 8B aligned
    const float2 vmask = make_float2(
        ((j <= 12) && (ce     < OW)) ? 1.f : 0.f,
        ((j <= 12) && (ce + 1 < OW)) ? 1.f : 0.f);

    // per-lane base pointers for this task's column pair
    const float* __restrict__ Xp = X + b * (IMH * IMW) + y0 * IMW + cin;
    const float* __restrict__ Yp = Y + b * (IMH * IMW) + y0 * IMW + cin;

    const float L     = data_range[b];
    const float C1    = (0.01f * L) * (0.01f * L);
    const float C2    = (0.03f * L) * (0.03f * L);
    const float inv49 = 1.0f / 49.0f;
    const float covn  = 49.0f / 48.0f;

    // per-lane raw history of its 2 columns + running vertical sums
    float2 xh[7], yh[7];
    #pragma unroll
    for (int k = 0; k < 7; ++k) { xh[k] = f2s(0.f); yh[k] = f2s(0.f); }
    float2 V0 = f2s(0.f), V1 = f2s(0.f), V2 = f2s(0.f),
           V3 = f2s(0.f), V4 = f2s(0.f);
    float2 ls2 = f2s(0.f);

    #pragma unroll
    for (int r = 0; r < INROWS; ++r) {
        // direct load; y0+r <= 369+14 = 383 -> always in range, no clamp.
        // 15 independent static-offset load pairs: scheduler hoists freely.
        const float2 x = *(const float2*)(Xp + r * IMW);
        const float2 y = *(const float2*)(Yp + r * IMW);

        // vertical 7-row slide on both columns (pk-f32 eligible)
        const int ks = r % 7;                          // static after unroll
        const float2 xo = xh[ks], yo = yh[ks];
        V0 = f2add(V0, f2sub(x, xo));
        V1 = f2add(V1, f2sub(y, yo));
        V2 = f2fma(x, x, V2);  V2 = f2fnma(xo, xo, V2);
        V3 = f2fma(x, y, V3);  V3 = f2fnma(xo, yo, V3);
        V4 = f2fma(y, y, V4);  V4 = f2fnma(yo, yo, V4);
        xh[ks] = x; yh[ks] = y;

        if (r >= 6) {   // output row o = y0+r-6; tiling guarantees o < OH
            // horizontal 7-window sums for even+odd output cols, 3 DPP each:
            //   pp(l) = e(l)+o(l)
            //   C(l)  = pp(l)+pp(l+1)+pp(l+2)+pp(l+3)   (2 shifted adds)
            //   Se(l) = cols 2l..2l+6   = C(l) - o(l+3)
            //   So(l) = cols 2l+1..2l+7 = C(l) - e(l)
            const float2 Vv[5] = {V0, V1, V2, V3, V4};
            float Se[5], So[5];
            #pragma unroll
            for (int p = 0; p < 5; ++p) {
                const float e  = Vv[p].x;
                const float o  = Vv[p].y;
                const float pp = e + o;
                float B = pp + dpp_sh<0x101>(pp);      // pp(l)+pp(l+1)
                float C = B + dpp_sh<0x102>(B);        // pp(l..l+3)
                Se[p] = C - dpp_sh<0x103>(o);          // cols 2l..2l+6
                So[p] = C - e;                         // cols 2l+1..2l+7
            }
            const float2 S0 = make_float2(Se[0], So[0]);
            const float2 S1 = make_float2(Se[1], So[1]);
            const float2 S2 = make_float2(Se[2], So[2]);
            const float2 S3 = make_float2(Se[3], So[3]);
            const float2 S4 = make_float2(Se[4], So[4]);

            float2 ux   = f2mul(S0, f2s(inv49));
            float2 uy   = f2mul(S1, f2s(inv49));
            float2 uxux = f2mul(ux, ux);
            float2 uyuy = f2mul(uy, uy);
            float2 uxuy = f2mul(ux, uy);
            float2 vx   = f2mul(f2fms(S2, inv49, uxux), f2s(covn));
            float2 vy   = f2mul(f2fms(S4, inv49, uyuy), f2s(covn));
            float2 vxy  = f2mul(f2fms(S3, inv49, uxuy), f2s(covn));
            float2 N1   = f2fma(f2s(2.f), uxuy, f2s(C1));
            float2 N2   = f2fma(f2s(2.f), vxy, f2s(C2));
            float2 D1   = f2add(f2add(uxux, uyuy), f2s(C1));
            float2 D2   = f2add(f2add(vx, vy), f2s(C2));
            float2 num  = f2mul(N1, N2);
            float2 den  = f2mul(D1, D2);
            // one rcp for both columns: se = nx*dy/(dx*dy), so = ny*dx/(dx*dy)
            const float rdd = __builtin_amdgcn_rcpf(den.x * den.y);
            float2 s2 = make_float2(num.x * den.y * rdd,
                                    num.y * den.x * rdd);
            ls2 = f2fma(s2, vmask, ls2);
        }
    }

    float lsum = ls2.x + ls2.y;

    // ---- per-group 16-lane reduce, then per-block <=2 atomics ----
    #pragma unroll
    for (int off = 8; off > 0; off >>= 1)
        lsum += __shfl_down(lsum, off, 16);

    __shared__ float gsum[16];
    __shared__ int   gb[16];
    if (j == 0) { gsum[g] = lsum; gb[g] = b; }
    __syncthreads();
    if (tid < 16) {
        const float v  = gsum[tid];
        const int   bv = gb[tid];
        const int   b0 = gb[0];
        const int   b1 = gb[15];
        float m0 = (bv == b0) ? v : 0.f;
        float m1 = (bv != b0) ? v : 0.f;
        #pragma unroll
        for (int off = 8; off > 0; off >>= 1) {
            m0 += __shfl_down(m0, off, 16);
            m1 += __shfl_down(m1, off, 16);
        }
        if (tid == 0) {
            atomicAdd(acc + b0 * ACCSTRIDE, m0);
            if (b1 != b0) atomicAdd(acc + b1 * ACCSTRIDE, m1);
        }
    }
}

__global__ void finalize_kernel(const float* __restrict__ acc,
                                float* __restrict__ out)
{
    float v = acc[threadIdx.x * ACCSTRIDE];   // 64 threads, one slot each
    #pragma unroll
    for (int off = 32; off > 0; off >>= 1)
        v += __shfl_down(v, off, 64);
    if (threadIdx.x == 0)
        out[0] = 1.0f - v * (1.0f / (float)(NB * OH * OW));
}

extern "C" void kernel_launch(void* const* d_in, const int* in_sizes, int n_in,
                              void* d_out, int out_size, void* d_ws, size_t ws_size,
                              hipStream_t stream) {
    const float* X  = (const float*)d_in[0];
    const float* Y  = (const float*)d_in[1];
    const float* dr = (const float*)d_in[2];
    float* out = (float*)d_out;
    float* acc = (float*)d_ws;

    hipMemsetAsync(acc, 0, NB * ACCSTRIDE * sizeof(float), stream);

    dim3 grid(NBLOCKS);         // 2520 blocks, 16 live group-tasks each
    dim3 block(BLOCK);          // 256 threads = 4 waves
    ssim_kernel<<<grid, block, 0, stream>>>(X, Y, dr, acc);
    finalize_kernel<<<1, 64, 0, stream>>>(acc, out);
}

// Round 5
// 32.786 us; speedup vs baseline: 1.0098x; 1.0098x over previous
//
#include <hip/hip_runtime.h>

#define IMH 384
#define IMW 384
#define OH 378
#define OW 378
#define NB 64
#define SROWS 9
#define INROWS 15          // SROWS + 6
#define NSTRIP 42          // 42*9 = 378 exactly
#define NSEG 15            // ceil(378/26) column segments per strip
#define BLOCK 256          // 4 waves = 16 DPP groups of 16 lanes
#define GSTRIDE 26         // output cols per group (13 lanes x 2 cols)
#define TPB (NSTRIP * NSEG)          // 630 tasks per batch
#define NTASK (NB * TPB)             // 40320 group-tasks
#define NBLOCKS (NTASK / 16)         // 2520 blocks, no dead groups
#define ACCSTRIDE 32                 // one 128B line per batch slot

// Round 14: R12 (2x waves) and R13 (scheduler freedom) both FLAT at ~33us.
// R11's 179us run proved overhead <1us -> ssim itself is ~32us and
// insensitive to occupancy/waves/scheduling. Revised theory: the allocator
// SINKS independent loads toward uses to save registers (R11 showed VGPR=40
// of an 85 budget), so pipeline depth stayed ~2 and each of 15 row steps
// exposes L2/HBM latency with all waves stalling in phase.
// Fix: issue ALL 30 row loads up front (one memory round-trip per wave),
// pinned with sched_barrier(0) so they cannot be sunk. History ring deleted:
// row r-7 is read straight from the row registers (-28 VGPR of dup state).
// waves_per_eu(5,8): ~102-reg budget for the ~95 live set.
// DIAGNOSTIC: VGPR_Count must rise to ~85-100. High VGPR + flat time would
// disprove latency-exposure -> R15 = cooperative LDS tiling for traffic.

template <int CTRL>
__device__ __forceinline__ float dpp_sh(float v) {
    return __int_as_float(__builtin_amdgcn_update_dpp(
        0, __float_as_int(v), CTRL, 0xf, 0xf, true));
}

__device__ __forceinline__ float2 f2add(float2 a, float2 b) { return make_float2(a.x + b.x, a.y + b.y); }
__device__ __forceinline__ float2 f2sub(float2 a, float2 b) { return make_float2(a.x - b.x, a.y - b.y); }
__device__ __forceinline__ float2 f2mul(float2 a, float2 b) { return make_float2(a.x * b.x, a.y * b.y); }
__device__ __forceinline__ float2 f2fma(float2 a, float2 b, float2 c) {
    return make_float2(fmaf(a.x, b.x, c.x), fmaf(a.y, b.y, c.y));
}
__device__ __forceinline__ float2 f2fnma(float2 a, float2 b, float2 c) {  // c - a*b
    return make_float2(fmaf(-a.x, b.x, c.x), fmaf(-a.y, b.y, c.y));
}
__device__ __forceinline__ float2 f2fms(float2 a, float s, float2 c) {    // a*s - c
    return make_float2(fmaf(a.x, s, -c.x), fmaf(a.y, s, -c.y));
}
__device__ __forceinline__ float2 f2s(float s) { return make_float2(s, s); }

__global__ __launch_bounds__(BLOCK)
__attribute__((amdgpu_waves_per_eu(5, 8)))
void ssim_kernel(
    const float* __restrict__ X, const float* __restrict__ Y,
    const float* __restrict__ data_range, float* __restrict__ acc)
{
    const int tid = threadIdx.x;
    const int g   = tid >> 4;                 // DPP group 0..15
    const int j   = tid & 15;                 // lane within group

    // ---- linearized task decode: t -> (b, strip, seg) ----
    const int t     = blockIdx.x * (BLOCK / 16) + g;
    const int b     = t / TPB;                      // /630 (magic mul)
    const int r2    = t - b * TPB;
    const int strip = r2 / NSEG;                    // /15
    const int seg   = r2 - strip * NSEG;
    const int y0    = strip * SROWS;

    const int ce  = seg * GSTRIDE + 2 * j;    // lane's even column (global)
    const int cin = min(ce, IMW - 2);         // clamped, even -> 8B aligned
    const float2 vmask = make_float2(
        ((j <= 12) && (ce     < OW)) ? 1.f : 0.f,
        ((j <= 12) && (ce + 1 < OW)) ? 1.f : 0.f);

    // per-lane base pointers for this task's column pair
    const float* __restrict__ Xp = X + b * (IMH * IMW) + y0 * IMW + cin;
    const float* __restrict__ Yp = Y + b * (IMH * IMW) + y0 * IMW + cin;

    // ---- issue ALL row loads up front: one HBM round-trip per wave ----
    float2 rx[INROWS], ry[INROWS];
    #pragma unroll
    for (int r = 0; r < INROWS; ++r) {
        rx[r] = *(const float2*)(Xp + r * IMW);   // y0+r <= 383, no clamp
        ry[r] = *(const float2*)(Yp + r * IMW);
    }
    // pin: no compute may be scheduled before all 30 loads are issued,
    // and loads cannot be sunk down into the compute loop.
    __builtin_amdgcn_sched_barrier(0);

    const float L     = data_range[b];
    const float C1    = (0.01f * L) * (0.01f * L);
    const float C2    = (0.03f * L) * (0.03f * L);
    const float inv49 = 1.0f / 49.0f;
    const float covn  = 49.0f / 48.0f;

    float2 V0 = f2s(0.f), V1 = f2s(0.f), V2 = f2s(0.f),
           V3 = f2s(0.f), V4 = f2s(0.f);
    float2 ls2 = f2s(0.f);

    #pragma unroll
    for (int r = 0; r < INROWS; ++r) {
        const float2 x = rx[r], y = ry[r];

        // vertical 7-row slide; r-7 read straight from row registers
        V0 = f2add(V0, x);
        V1 = f2add(V1, y);
        V2 = f2fma(x, x, V2);
        V3 = f2fma(x, y, V3);
        V4 = f2fma(y, y, V4);
        if (r >= 7) {
            const float2 xo = rx[r - 7], yo = ry[r - 7];
            V0 = f2sub(V0, xo);
            V1 = f2sub(V1, yo);
            V2 = f2fnma(xo, xo, V2);
            V3 = f2fnma(xo, yo, V3);
            V4 = f2fnma(yo, yo, V4);
        }

        if (r >= 6) {   // output row o = y0+r-6; tiling guarantees o < OH
            // horizontal 7-window sums for even+odd output cols, 3 DPP each:
            //   pp(l) = e(l)+o(l)
            //   C(l)  = pp(l)+pp(l+1)+pp(l+2)+pp(l+3)   (2 shifted adds)
            //   Se(l) = cols 2l..2l+6   = C(l) - o(l+3)
            //   So(l) = cols 2l+1..2l+7 = C(l) - e(l)
            const float2 Vv[5] = {V0, V1, V2, V3, V4};
            float Se[5], So[5];
            #pragma unroll
            for (int p = 0; p < 5; ++p) {
                const float e  = Vv[p].x;
                const float o  = Vv[p].y;
                const float pp = e + o;
                float B = pp + dpp_sh<0x101>(pp);      // pp(l)+pp(l+1)
                float C = B + dpp_sh<0x102>(B);        // pp(l..l+3)
                Se[p] = C - dpp_sh<0x103>(o);          // cols 2l..2l+6
                So[p] = C - e;                         // cols 2l+1..2l+7
            }
            const float2 S0 = make_float2(Se[0], So[0]);
            const float2 S1 = make_float2(Se[1], So[1]);
            const float2 S2 = make_float2(Se[2], So[2]);
            const float2 S3 = make_float2(Se[3], So[3]);
            const float2 S4 = make_float2(Se[4], So[4]);

            float2 ux   = f2mul(S0, f2s(inv49));
            float2 uy   = f2mul(S1, f2s(inv49));
            float2 uxux = f2mul(ux, ux);
            float2 uyuy = f2mul(uy, uy);
            float2 uxuy = f2mul(ux, uy);
            float2 vx   = f2mul(f2fms(S2, inv49, uxux), f2s(covn));
            float2 vy   = f2mul(f2fms(S4, inv49, uyuy), f2s(covn));
            float2 vxy  = f2mul(f2fms(S3, inv49, uxuy), f2s(covn));
            float2 N1   = f2fma(f2s(2.f), uxuy, f2s(C1));
            float2 N2   = f2fma(f2s(2.f), vxy, f2s(C2));
            float2 D1   = f2add(f2add(uxux, uyuy), f2s(C1));
            float2 D2   = f2add(f2add(vx, vy), f2s(C2));
            float2 num  = f2mul(N1, N2);
            float2 den  = f2mul(D1, D2);
            // one rcp for both columns: se = nx*dy/(dx*dy), so = ny*dx/(dx*dy)
            const float rdd = __builtin_amdgcn_rcpf(den.x * den.y);
            float2 s2 = make_float2(num.x * den.y * rdd,
                                    num.y * den.x * rdd);
            ls2 = f2fma(s2, vmask, ls2);
        }
    }

    float lsum = ls2.x + ls2.y;

    // ---- per-group 16-lane reduce, then per-block <=2 atomics ----
    #pragma unroll
    for (int off = 8; off > 0; off >>= 1)
        lsum += __shfl_down(lsum, off, 16);

    __shared__ float gsum[16];
    __shared__ int   gb[16];
    if (j == 0) { gsum[g] = lsum; gb[g] = b; }
    __syncthreads();
    if (tid < 16) {
        const float v  = gsum[tid];
        const int   bv = gb[tid];
        const int   b0 = gb[0];
        const int   b1 = gb[15];
        float m0 = (bv == b0) ? v : 0.f;
        float m1 = (bv != b0) ? v : 0.f;
        #pragma unroll
        for (int off = 8; off > 0; off >>= 1) {
            m0 += __shfl_down(m0, off, 16);
            m1 += __shfl_down(m1, off, 16);
        }
        if (tid == 0) {
            atomicAdd(acc + b0 * ACCSTRIDE, m0);
            if (b1 != b0) atomicAdd(acc + b1 * ACCSTRIDE, m1);
        }
    }
}

__global__ void finalize_kernel(const float* __restrict__ acc,
                                float* __restrict__ out)
{
    float v = acc[threadIdx.x * ACCSTRIDE];   // 64 threads, one slot each
    #pragma unroll
    for (int off = 32; off > 0; off >>= 1)
        v += __shfl_down(v, off, 64);
    if (threadIdx.x == 0)
        out[0] = 1.0f - v * (1.0f / (float)(NB * OH * OW));
}

extern "C" void kernel_launch(void* const* d_in, const int* in_sizes, int n_in,
                              void* d_out, int out_size, void* d_ws, size_t ws_size,
                              hipStream_t stream) {
    const float* X  = (const float*)d_in[0];
    const float* Y  = (const float*)d_in[1];
    const float* dr = (const float*)d_in[2];
    float* out = (float*)d_out;
    float* acc = (float*)d_ws;

    hipMemsetAsync(acc, 0, NB * ACCSTRIDE * sizeof(float), stream);

    dim3 grid(NBLOCKS);         // 2520 blocks, 16 live group-tasks each
    dim3 block(BLOCK);          // 256 threads = 4 waves
    ssim_kernel<<<grid, block, 0, stream>>>(X, Y, dr, acc);
    finalize_kernel<<<1, 64, 0, stream>>>(acc, out);
}

// Round 7
// 31.388 us; speedup vs baseline: 1.0547x; 1.0445x over previous
//
#include <hip/hip_runtime.h>

#define IMH 384
#define IMW 384
#define OH 378
#define OW 378
#define NB 64
#define SROWS 21
#define INROWS 27          // SROWS + 6
#define NSTRIP 18          // 18*21 = 378 exactly
#define BLOCK 256          // 4 waves = 16 DPP groups of 16 lanes
#define GSTRIDE 26         // output cols per group (13 lanes x 2 cols)
#define RING 6             // LDS row-ring depth

// Round 16 = Round 15 resubmitted verbatim: the R15 bench died with
// UnresponsiveContainer BEFORE the job ran (infra, not kernel). Kernel
// re-audited: all barriers block-uniform, ring slot writes/reads separated
// by >=1 barrier, all addresses in bounds, no spin/coop constructs ->
// nothing that can hang hardware. Hypothesis under test is unchanged:
//
// R12 (2x waves), R13 (sched freedom), R14 (forced full prefetch) all FLAT
// at ~33us -> latency exposure falsified. Remaining model: ~19us VALU +
// ~20us HBM (126-155MB redundant traffic, L3 evicted by poison fills).
// This round attacks the only hard floor never touched: HBM bytes.
//   - Block-cooperative full-width LDS staging: block=(strip,b), rows staged
//     ONCE (384 floats x2), horizontal redundancy 1.23->1.0; SROWS=21 ->
//     vertical 27/21=1.286. Traffic ~95MB (was ~126-155).
//   - 6-slot LDS ring, ds_write head +5 rows, global loads +8 rows via
//     3-deep reg FIFO (async split), ONE barrier/row. Waves 0-2 stage
//     (tid<192: uniform per wave), all 4 waves compute.
//   - Per-lane VMEM instrs per row: 2 -> 0 (amortized 0.75/block-row).
//   - No atomics, no memset: plain per-block partial store + tiny reducer.
// Prediction: LDS 18.4KB, VGPR 72-90, FETCH ~95MB, dur -> 20-24us if
// memory-throughput-bound; flat would falsify traffic too -> R17 ablation.

template <int CTRL>
__device__ __forceinline__ float dpp_sh(float v) {
    return __int_as_float(__builtin_amdgcn_update_dpp(
        0, __float_as_int(v), CTRL, 0xf, 0xf, true));
}

__device__ __forceinline__ float2 f2add(float2 a, float2 b) { return make_float2(a.x + b.x, a.y + b.y); }
__device__ __forceinline__ float2 f2sub(float2 a, float2 b) { return make_float2(a.x - b.x, a.y - b.y); }
__device__ __forceinline__ float2 f2mul(float2 a, float2 b) { return make_float2(a.x * b.x, a.y * b.y); }
__device__ __forceinline__ float2 f2fma(float2 a, float2 b, float2 c) {
    return make_float2(fmaf(a.x, b.x, c.x), fmaf(a.y, b.y, c.y));
}
__device__ __forceinline__ float2 f2fnma(float2 a, float2 b, float2 c) {  // c - a*b
    return make_float2(fmaf(-a.x, b.x, c.x), fmaf(-a.y, b.y, c.y));
}
__device__ __forceinline__ float2 f2fms(float2 a, float s, float2 c) {    // a*s - c
    return make_float2(fmaf(a.x, s, -c.x), fmaf(a.y, s, -c.y));
}
__device__ __forceinline__ float2 f2s(float s) { return make_float2(s, s); }

__global__ __launch_bounds__(BLOCK)
__attribute__((amdgpu_waves_per_eu(5, 8)))
void ssim_kernel(
    const float* __restrict__ X, const float* __restrict__ Y,
    const float* __restrict__ data_range, float* __restrict__ partials)
{
    const int tid   = threadIdx.x;
    const int g     = tid >> 4;               // DPP group 0..15
    const int j     = tid & 15;               // lane within group
    const int strip = blockIdx.x;
    const int b     = blockIdx.y;
    const int y0    = strip * SROWS;          // <= 357; +26 = 383, in range

    const float* __restrict__ Xb = X + b * (IMH * IMW);
    const float* __restrict__ Yb = Y + b * (IMH * IMW);

    __shared__ float sX[RING][IMW];
    __shared__ float sY[RING][IMW];

    // ---- staging role: waves 0-2 (tid<192) stage; no intra-wave divergence
    const bool stg = (tid < 192);
    const int  sc  = ((tid < 96) ? tid : tid - 96) * 4;        // col of float4
    const float* __restrict__ gp =
        ((tid < 96) ? Xb : Yb) + y0 * IMW + sc;                // row-0 addr
    float* const sbase = (tid < 96) ? &sX[0][0] : &sY[0][0];

    // compute-side column mapping (identical to R12)
    const int ce  = g * GSTRIDE + 2 * j;      // lane's even column (global)
    const int cin = min(ce, IMW - 2);         // clamped, even -> 8B aligned
    const float2 vmask = make_float2(
        ((j <= 12) && (ce     < OW)) ? 1.f : 0.f,
        ((j <= 12) && (ce + 1 < OW)) ? 1.f : 0.f);

    const float L     = data_range[b];
    const float C1    = (0.01f * L) * (0.01f * L);
    const float C2    = (0.03f * L) * (0.03f * L);
    const float inv49 = 1.0f / 49.0f;
    const float covn  = 49.0f / 48.0f;

    // ---- prologue: stage rows 0..4 directly; preload rows 5,6,7 to regs
    if (stg) {
        #pragma unroll
        for (int k = 0; k < 5; ++k) {
            const float4 v = *(const float4*)(gp + k * IMW);
            *(float4*)(sbase + k * IMW + sc) = v;
        }
    }
    float4 gb0, gb1, gb2;
    if (stg) {
        gb0 = *(const float4*)(gp + 5 * IMW);
        gb1 = *(const float4*)(gp + 6 * IMW);
        gb2 = *(const float4*)(gp + 7 * IMW);
    }
    __syncthreads();

    // per-lane raw history + running vertical sums
    float2 xh[7], yh[7];
    #pragma unroll
    for (int k = 0; k < 7; ++k) { xh[k] = f2s(0.f); yh[k] = f2s(0.f); }
    float2 V0 = f2s(0.f), V1 = f2s(0.f), V2 = f2s(0.f),
           V3 = f2s(0.f), V4 = f2s(0.f);
    float2 ls2 = f2s(0.f);

    #pragma unroll
    for (int r = 0; r < INROWS; ++r) {
        // (1) write pending row r+5 (loaded 3 iters ago) into its slot
        if (r + 5 < INROWS) {
            if (stg) {
                const float4 v = (r % 3 == 0) ? gb0 : (r % 3 == 1) ? gb1 : gb2;
                *(float4*)(sbase + ((r + 5) % RING) * IMW + sc) = v;
            }
        }
        // (2) issue load of row r+8 into the freed FIFO slot
        if (r + 8 < INROWS) {
            if (stg) {
                const float4 v = *(const float4*)(gp + (r + 8) * IMW);
                if (r % 3 == 0) gb0 = v; else if (r % 3 == 1) gb1 = v; else gb2 = v;
            }
        }

        // (3) compute row r from slot r%RING
        const float2 x = *(const float2*)&sX[r % RING][cin];
        const float2 y = *(const float2*)&sY[r % RING][cin];

        const int ks = r % 7;                          // static after unroll
        const float2 xo = xh[ks], yo = yh[ks];
        V0 = f2add(V0, f2sub(x, xo));
        V1 = f2add(V1, f2sub(y, yo));
        V2 = f2fma(x, x, V2);  V2 = f2fnma(xo, xo, V2);
        V3 = f2fma(x, y, V3);  V3 = f2fnma(xo, yo, V3);
        V4 = f2fma(y, y, V4);  V4 = f2fnma(yo, yo, V4);
        xh[ks] = x; yh[ks] = y;

        if (r >= 6) {   // output row o = y0+r-6 < OH by tiling
            const float2 Vv[5] = {V0, V1, V2, V3, V4};
            float Se[5], So[5];
            #pragma unroll
            for (int p = 0; p < 5; ++p) {
                const float e  = Vv[p].x;
                const float o  = Vv[p].y;
                const float pp = e + o;
                float B = pp + dpp_sh<0x101>(pp);      // pp(l)+pp(l+1)
                float C = B + dpp_sh<0x102>(B);        // pp(l..l+3)
                Se[p] = C - dpp_sh<0x103>(o);          // cols 2l..2l+6
                So[p] = C - e;                         // cols 2l+1..2l+7
            }
            const float2 S0 = make_float2(Se[0], So[0]);
            const float2 S1 = make_float2(Se[1], So[1]);
            const float2 S2 = make_float2(Se[2], So[2]);
            const float2 S3 = make_float2(Se[3], So[3]);
            const float2 S4 = make_float2(Se[4], So[4]);

            float2 ux   = f2mul(S0, f2s(inv49));
            float2 uy   = f2mul(S1, f2s(inv49));
            float2 uxux = f2mul(ux, ux);
            float2 uyuy = f2mul(uy, uy);
            float2 uxuy = f2mul(ux, uy);
            float2 vx   = f2mul(f2fms(S2, inv49, uxux), f2s(covn));
            float2 vy   = f2mul(f2fms(S4, inv49, uyuy), f2s(covn));
            float2 vxy  = f2mul(f2fms(S3, inv49, uxuy), f2s(covn));
            float2 N1   = f2fma(f2s(2.f), uxuy, f2s(C1));
            float2 N2   = f2fma(f2s(2.f), vxy, f2s(C2));
            float2 D1   = f2add(f2add(uxux, uyuy), f2s(C1));
            float2 D2   = f2add(f2add(vx, vy), f2s(C2));
            float2 num  = f2mul(N1, N2);
            float2 den  = f2mul(D1, D2);
            const float rdd = __builtin_amdgcn_rcpf(den.x * den.y);
            float2 s2 = make_float2(num.x * den.y * rdd,
                                    num.y * den.x * rdd);
            ls2 = f2fma(s2, vmask, ls2);
        }

        // (4) one barrier per row: stage(r+5) visible later; slot r%RING
        // may be overwritten next iter only after all waves read it.
        __syncthreads();
    }

    // ---- block reduction (single batch per block) -> plain store ----
    float lsum = ls2.x + ls2.y;
    __shared__ float red[BLOCK / 64];
    #pragma unroll
    for (int off = 32; off > 0; off >>= 1)
        lsum += __shfl_down(lsum, off, 64);
    if ((tid & 63) == 0) red[tid >> 6] = lsum;
    __syncthreads();
    if (tid == 0) {
        float bs = 0.f;
        #pragma unroll
        for (int k = 0; k < BLOCK / 64; ++k) bs += red[k];
        partials[b * NSTRIP + strip] = bs;    // no atomic, no memset needed
    }
}

__global__ void finalize_kernel(const float* __restrict__ partials,
                                float* __restrict__ out)
{
    // 64 threads reduce NB*NSTRIP = 1152 partials
    float v = 0.f;
    #pragma unroll
    for (int k = 0; k < NSTRIP; ++k)
        v += partials[threadIdx.x + 64 * k];
    #pragma unroll
    for (int off = 32; off > 0; off >>= 1)
        v += __shfl_down(v, off, 64);
    if (threadIdx.x == 0)
        out[0] = 1.0f - v * (1.0f / (float)(NB * OH * OW));
}

extern "C" void kernel_launch(void* const* d_in, const int* in_sizes, int n_in,
                              void* d_out, int out_size, void* d_ws, size_t ws_size,
                              hipStream_t stream) {
    const float* X  = (const float*)d_in[0];
    const float* Y  = (const float*)d_in[1];
    const float* dr = (const float*)d_in[2];
    float* out = (float*)d_out;
    float* partials = (float*)d_ws;           // NB*NSTRIP floats, fully written

    dim3 grid(NSTRIP, NB);      // 18 x 64 = 1152 blocks
    dim3 block(BLOCK);          // 256 threads = 4 waves
    ssim_kernel<<<grid, block, 0, stream>>>(X, Y, dr, partials);
    finalize_kernel<<<1, 64, 0, stream>>>(partials, out);
}

// Round 8
// 28.202 us; speedup vs baseline: 1.1739x; 1.1130x over previous
//
#include <hip/hip_runtime.h>

#define IMH 384
#define IMW 384
#define OH 378
#define OW 378
#define NB 64
#define SROWS 21
#define INROWS 27          // SROWS + 6
#define NSTRIP 18          // 18*21 = 378 exactly
#define BLOCK 256          // 4 waves = 16 DPP groups of 16 lanes
#define GSTRIDE 26         // output cols per group (13 lanes x 2 cols)
#define RING 8             // LDS row-ring slots per tensor
#define LA 6               // DMA lookahead (rows in flight per wave)
#define SLOTF 512          // floats per slot: 384 data + 128 pad (2048 B)

// Round 17: R15/16 (LDS staging, -35% traffic) gave only 31.4us -> BW
// falsified. Re-audit: R13/R14's prefetch experiments were INVALID — the
// register budget (~102) cannot hold 30 float2 loads live, so effective
// depth stayed ~2-3; R15's reg-FIFO was 3 deep AND __syncthreads drained
// vmcnt(0) every row. Deep prefetch was never actually tested.
// This round: global_load_lds DMA ring — the only mechanism with ZERO
// register cost for depth. 8-slot LDS ring/tensor, 6-row lookahead,
// counted s_waitcnt vmcnt(6) (NEVER 0 in the main loop) + raw s_barrier
// (no compiler vmcnt drain). Each wave issues exactly 1 DMA per row:
// waves 0/1 = X low/high half-row, waves 2/3 = Y (pad lanes clamp to the
// last 16B of the row; land in slot pad region). Slot reuse distance =
// RING-LA = 2 barriers -> race-free. LDS exactly 32KB -> 5 blocks/CU.
// PREDICTION: VGPR 60-80, LDS 32768, FETCH ~95MB; 17-22us if the latency
// theory is right; flat ~31us kills it -> R18 = VALU/DS chain reduction.

template <int CTRL>
__device__ __forceinline__ float dpp_sh(float v) {
    return __int_as_float(__builtin_amdgcn_update_dpp(
        0, __float_as_int(v), CTRL, 0xf, 0xf, true));
}

__device__ __forceinline__ float2 f2add(float2 a, float2 b) { return make_float2(a.x + b.x, a.y + b.y); }
__device__ __forceinline__ float2 f2sub(float2 a, float2 b) { return make_float2(a.x - b.x, a.y - b.y); }
__device__ __forceinline__ float2 f2mul(float2 a, float2 b) { return make_float2(a.x * b.x, a.y * b.y); }
__device__ __forceinline__ float2 f2fma(float2 a, float2 b, float2 c) {
    return make_float2(fmaf(a.x, b.x, c.x), fmaf(a.y, b.y, c.y));
}
__device__ __forceinline__ float2 f2fnma(float2 a, float2 b, float2 c) {  // c - a*b
    return make_float2(fmaf(-a.x, b.x, c.x), fmaf(-a.y, b.y, c.y));
}
__device__ __forceinline__ float2 f2fms(float2 a, float s, float2 c) {    // a*s - c
    return make_float2(fmaf(a.x, s, -c.x), fmaf(a.y, s, -c.y));
}
__device__ __forceinline__ float2 f2s(float s) { return make_float2(s, s); }

// async global->LDS DMA, 16B per lane; lds dest = wave-uniform base + lane*16
__device__ __forceinline__ void stage16(const float* g, float* l) {
    __builtin_amdgcn_global_load_lds(
        (const __attribute__((address_space(1))) uint32_t*)(g),
        (__attribute__((address_space(3))) uint32_t*)(l),
        16, 0, 0);
}

#define WAITV(n) asm volatile("s_waitcnt vmcnt(" #n ")" ::: "memory")
#define RAWBAR() asm volatile("s_barrier" ::: "memory")

__global__ __launch_bounds__(BLOCK)
__attribute__((amdgpu_waves_per_eu(5, 8)))
void ssim_kernel(
    const float* __restrict__ X, const float* __restrict__ Y,
    const float* __restrict__ data_range, float* __restrict__ partials)
{
    const int tid   = threadIdx.x;
    const int g     = tid >> 4;               // DPP group 0..15
    const int j     = tid & 15;               // lane within group
    const int strip = blockIdx.x;
    const int b     = blockIdx.y;
    const int y0    = strip * SROWS;          // <= 357; +26 = 383 in range

    __shared__ float sX[RING][SLOTF];
    __shared__ float sY[RING][SLOTF];

    // ---- staging role: every wave DMAs one half-row of one tensor ----
    const int wv   = tid >> 6;                // wave 0..3
    const int ln   = tid & 63;
    const bool isX = (wv < 2);
    const int half = wv & 1;                  // 0: floats 0..255, 1: 256..511
    const int foff = half * 256 + ln * 4;     // float col of this lane's 16B
    const int fcl  = min(foff, IMW - 4);      // pad lanes re-read last 16B
    const float* __restrict__ gstg =
        (isX ? X : Y) + b * (IMH * IMW) + y0 * IMW + fcl;
    float* const lstg = (isX ? &sX[0][0] : &sY[0][0]) + foff;  // = base+ln*16B

    // compute-side column mapping (unchanged)
    const int ce  = g * GSTRIDE + 2 * j;      // lane's even column (global)
    const int cin = min(ce, IMW - 2);         // clamped, even -> 8B aligned
    const float2 vmask = make_float2(
        ((j <= 12) && (ce     < OW)) ? 1.f : 0.f,
        ((j <= 12) && (ce + 1 < OW)) ? 1.f : 0.f);

    // finish the data_range load (and its compiler waitcnt) BEFORE any DMA
    const float L  = data_range[b];
    const float C1 = (0.01f * L) * (0.01f * L);
    const float C2 = (0.03f * L) * (0.03f * L);
    asm volatile("" :: "v"(C1), "v"(C2));
    __builtin_amdgcn_sched_barrier(0);

    // ---- prologue: DMA rows 0..LA-1 into slots 0..LA-1 ----
    #pragma unroll
    for (int k = 0; k < LA; ++k)
        stage16(gstg + k * IMW, lstg + k * SLOTF);

    const float inv49 = 1.0f / 49.0f;
    const float covn  = 49.0f / 48.0f;

    float2 xh[7], yh[7];
    #pragma unroll
    for (int k = 0; k < 7; ++k) { xh[k] = f2s(0.f); yh[k] = f2s(0.f); }
    float2 V0 = f2s(0.f), V1 = f2s(0.f), V2 = f2s(0.f),
           V3 = f2s(0.f), V4 = f2s(0.f);
    float2 ls2 = f2s(0.f);

    static_assert(INROWS == 27 && LA == 6 && RING == 8, "wait ladder");

    #pragma unroll
    for (int r = 0; r < INROWS; ++r) {
        // issue DMA for row r+LA into slot (r+LA)%RING (reuse distance 2)
        if (r + LA < INROWS)
            stage16(gstg + (r + LA) * IMW, lstg + ((r + LA) % RING) * SLOTF);

        // wait: own oldest outstanding (row r) done; never drain to 0
        if      (r < 21) WAITV(6);
        else if (r == 21) WAITV(5);
        else if (r == 22) WAITV(4);
        else if (r == 23) WAITV(3);
        else if (r == 24) WAITV(2);
        else if (r == 25) WAITV(1);
        else              WAITV(0);
        RAWBAR();                     // all waves' row-r DMAs complete

        // compute row r from slot r%RING
        const float2 x = *(const float2*)&sX[r % RING][cin];
        const float2 y = *(const float2*)&sY[r % RING][cin];

        const int ks = r % 7;                          // static after unroll
        const float2 xo = xh[ks], yo = yh[ks];
        V0 = f2add(V0, f2sub(x, xo));
        V1 = f2add(V1, f2sub(y, yo));
        V2 = f2fma(x, x, V2);  V2 = f2fnma(xo, xo, V2);
        V3 = f2fma(x, y, V3);  V3 = f2fnma(xo, yo, V3);
        V4 = f2fma(y, y, V4);  V4 = f2fnma(yo, yo, V4);
        xh[ks] = x; yh[ks] = y;

        if (r >= 6) {   // output row o = y0+r-6 < OH by tiling
            const float2 Vv[5] = {V0, V1, V2, V3, V4};
            float Se[5], So[5];
            #pragma unroll
            for (int p = 0; p < 5; ++p) {
                const float e  = Vv[p].x;
                const float o  = Vv[p].y;
                const float pp = e + o;
                float B = pp + dpp_sh<0x101>(pp);      // pp(l)+pp(l+1)
                float C = B + dpp_sh<0x102>(B);        // pp(l..l+3)
                Se[p] = C - dpp_sh<0x103>(o);          // cols 2l..2l+6
                So[p] = C - e;                         // cols 2l+1..2l+7
            }
            const float2 S0 = make_float2(Se[0], So[0]);
            const float2 S1 = make_float2(Se[1], So[1]);
            const float2 S2 = make_float2(Se[2], So[2]);
            const float2 S3 = make_float2(Se[3], So[3]);
            const float2 S4 = make_float2(Se[4], So[4]);

            float2 ux   = f2mul(S0, f2s(inv49));
            float2 uy   = f2mul(S1, f2s(inv49));
            float2 uxux = f2mul(ux, ux);
            float2 uyuy = f2mul(uy, uy);
            float2 uxuy = f2mul(ux, uy);
            float2 vx   = f2mul(f2fms(S2, inv49, uxux), f2s(covn));
            float2 vy   = f2mul(f2fms(S4, inv49, uyuy), f2s(covn));
            float2 vxy  = f2mul(f2fms(S3, inv49, uxuy), f2s(covn));
            float2 N1   = f2fma(f2s(2.f), uxuy, f2s(C1));
            float2 N2   = f2fma(f2s(2.f), vxy, f2s(C2));
            float2 D1   = f2add(f2add(uxux, uyuy), f2s(C1));
            float2 D2   = f2add(f2add(vx, vy), f2s(C2));
            float2 num  = f2mul(N1, N2);
            float2 den  = f2mul(D1, D2);
            const float rdd = __builtin_amdgcn_rcpf(den.x * den.y);
            float2 s2 = make_float2(num.x * den.y * rdd,
                                    num.y * den.x * rdd);
            ls2 = f2fma(s2, vmask, ls2);
        }
    }

    // ---- block reduction -> plain store (reuse sX, saves LDS) ----
    float lsum = ls2.x + ls2.y;
    #pragma unroll
    for (int off = 32; off > 0; off >>= 1)
        lsum += __shfl_down(lsum, off, 64);
    __syncthreads();                          // loop fully done, LDS free
    if ((tid & 63) == 0) sX[0][tid >> 6] = lsum;
    __syncthreads();
    if (tid == 0) {
        partials[b * NSTRIP + strip] =
            sX[0][0] + sX[0][1] + sX[0][2] + sX[0][3];
    }
}

__global__ void finalize_kernel(const float* __restrict__ partials,
                                float* __restrict__ out)
{
    float v = 0.f;
    #pragma unroll
    for (int k = 0; k < NSTRIP; ++k)
        v += partials[threadIdx.x + 64 * k];
    #pragma unroll
    for (int off = 32; off > 0; off >>= 1)
        v += __shfl_down(v, off, 64);
    if (threadIdx.x == 0)
        out[0] = 1.0f - v * (1.0f / (float)(NB * OH * OW));
}

extern "C" void kernel_launch(void* const* d_in, const int* in_sizes, int n_in,
                              void* d_out, int out_size, void* d_ws, size_t ws_size,
                              hipStream_t stream) {
    const float* X  = (const float*)d_in[0];
    const float* Y  = (const float*)d_in[1];
    const float* dr = (const float*)d_in[2];
    float* out = (float*)d_out;
    float* partials = (float*)d_ws;           // NB*NSTRIP floats, fully written

    dim3 grid(NSTRIP, NB);      // 18 x 64 = 1152 blocks
    dim3 block(BLOCK);          // 256 threads = 4 waves
    ssim_kernel<<<grid, block, 0, stream>>>(X, Y, dr, partials);
    finalize_kernel<<<1, 64, 0, stream>>>(partials, out);
}